// Round 2
// baseline (531.173 us; speedup 1.0000x reference)
//
#include <hip/hip_runtime.h>
#include <math.h>

#define B_   64
#define N_   1024
#define FIN_ 256
#define FO_  64

// ---------------------------------------------------------------------------
// Kernel 1: h = input @ W   (M = 65536 rows, K=256, N=64), e2 = h . a2 fused.
// 64-row x 64-col tile, 256 threads, 4x4 per thread, grid 1024 (4 blocks/CU).
// Register-prefetch of next K-chunk hides global latency under the FMA loop.
// ---------------------------------------------------------------------------
__global__ __launch_bounds__(256, 4) void k1_hproj(
    const float* __restrict__ input,   // [M][256]
    const float* __restrict__ W,       // [256][64]
    const float* __restrict__ a,       // [128]
    float* __restrict__ h,             // [M][64]
    float* __restrict__ e2)            // [M]
{
    __shared__ float in_lds[64][65];   // 65: row+k banks all distinct for af reads
    __shared__ float W_lds[64][64];

    const int t   = threadIdx.x;
    const int tx  = t & 15;            // f quad
    const int tyg = t >> 4;            // 0..15 -> rows tyg*4..+3
    const int r0  = blockIdx.x * 64;

    float acc[4][4] = {};
    float4 ireg[4], wreg[4];

    auto load_chunk = [&](int k0) {
        #pragma unroll
        for (int it = 0; it < 4; ++it) {
            const int idx = it * 256 + t;
            const int row = idx >> 4;
            const int kq  = (idx & 15) * 4;
            ireg[it] = *reinterpret_cast<const float4*>(
                &input[(size_t)(r0 + row) * FIN_ + k0 + kq]);
            wreg[it] = *reinterpret_cast<const float4*>(
                &W[(size_t)(k0 + row) * FO_ + kq]);
        }
    };
    auto store_chunk = [&]() {
        #pragma unroll
        for (int it = 0; it < 4; ++it) {
            const int idx = it * 256 + t;
            const int row = idx >> 4;
            const int kq  = (idx & 15) * 4;
            in_lds[row][kq + 0] = ireg[it].x;
            in_lds[row][kq + 1] = ireg[it].y;
            in_lds[row][kq + 2] = ireg[it].z;
            in_lds[row][kq + 3] = ireg[it].w;
            *reinterpret_cast<float4*>(&W_lds[row][kq]) = wreg[it];
        }
    };

    load_chunk(0);
    #pragma unroll 1
    for (int c = 0; c < 4; ++c) {
        store_chunk();
        __syncthreads();
        if (c < 3) load_chunk((c + 1) * 64);   // in flight during FMA loop
        #pragma unroll 4
        for (int k = 0; k < 64; ++k) {
            float af[4];
            #pragma unroll
            for (int mi = 0; mi < 4; ++mi) af[mi] = in_lds[tyg * 4 + mi][k];
            const float4 bf = *reinterpret_cast<const float4*>(&W_lds[k][tx * 4]);
            #pragma unroll
            for (int mi = 0; mi < 4; ++mi) {
                acc[mi][0] = fmaf(af[mi], bf.x, acc[mi][0]);
                acc[mi][1] = fmaf(af[mi], bf.y, acc[mi][1]);
                acc[mi][2] = fmaf(af[mi], bf.z, acc[mi][2]);
                acc[mi][3] = fmaf(af[mi], bf.w, acc[mi][3]);
            }
        }
        __syncthreads();
    }

    const float4 a2v = *reinterpret_cast<const float4*>(&a[FO_ + tx * 4]);
    #pragma unroll
    for (int mi = 0; mi < 4; ++mi) {
        const int row = r0 + tyg * 4 + mi;
        float4 hv;
        hv.x = acc[mi][0]; hv.y = acc[mi][1]; hv.z = acc[mi][2]; hv.w = acc[mi][3];
        *reinterpret_cast<float4*>(&h[(size_t)row * FO_ + tx * 4]) = hv;
        float p = acc[mi][0] * a2v.x + acc[mi][1] * a2v.y +
                  acc[mi][2] * a2v.z + acc[mi][3] * a2v.w;
        p += __shfl_xor(p, 1);
        p += __shfl_xor(p, 2);
        p += __shfl_xor(p, 4);
        p += __shfl_xor(p, 8);
        if (tx == 0) e2[row] = p;
    }
}

// ---------------------------------------------------------------------------
// Kernel 2: fused masked softmax attention + PV + ELU.
//   e1 collapses: idx=(i*64+f)//1024 == i//16 for all f -> e1[b,i,j]=S1*h[b,i,j>>4]
//   w = adj ? exp(relu(S1*h[b,i,j>>4] + e2[b,j])) : 0   (single pass, no max:
//   unmasked e in [0,~45], exp and f32 sums can't overflow; masked weight = 0
//   exactly, matching the reference's exp(-9e15-m) underflow).
// 64 i-rows/block -> grid 16x64 = 1024 blocks (4/CU). Fully pipelined:
// double-buffered h_lds+wT, register prefetch 1 tile ahead, 1 barrier/tile.
// ---------------------------------------------------------------------------
__global__ __launch_bounds__(256, 4) void k2_attn(
    const float* __restrict__ h,
    const int*   __restrict__ adj,
    const float* __restrict__ a,
    const float* __restrict__ e2,
    float* __restrict__ out)
{
    __shared__ float h_lds[2][32][64];   // [buf][j][f]
    __shared__ float wT[2][32][64];      // [buf][j][i]
    __shared__ float den_lds[64][4];

    const int t   = threadIdx.x;
    const int tx  = t & 15;              // f quad (GEMM)
    const int tyg = t >> 4;              // 0..15 -> rows tyg*4..+3 (GEMM)
    const int b   = blockIdx.y;
    const int i0  = blockIdx.x * 64;

    const int wi  = t >> 2;              // 0..63: weight-phase i-row
    const int ws  = t & 3;               // j octet
    const int jl0 = ws * 8;

    const float* hb     = h + (size_t)b * N_ * FO_;
    const float* e2b    = e2 + (size_t)b * N_;
    const int*   adjrow = adj + ((size_t)b * N_ + i0 + wi) * N_;

    float S1 = 0.f;
    #pragma unroll
    for (int f = 0; f < FO_; f += 4) {
        const float4 av = *reinterpret_cast<const float4*>(&a[f]);
        S1 += av.x + av.y + av.z + av.w;
    }

    float acc[4][4] = {};
    float denreg = 0.f;

    int4   areg[2];
    float4 hreg[2];
    float4 e2reg[2];
    float2 c2reg;

    auto prefetch = [&](int tile) {      // loads for tile (0..31) -> registers
        const int jt = tile * 32;
        areg[0] = *reinterpret_cast<const int4*>(&adjrow[jt + jl0]);
        areg[1] = *reinterpret_cast<const int4*>(&adjrow[jt + jl0 + 4]);
        #pragma unroll
        for (int it = 0; it < 2; ++it) {
            const int idx = it * 256 + t;
            const int j = idx >> 4, fq = (idx & 15) * 4;
            hreg[it] = *reinterpret_cast<const float4*>(
                &hb[(size_t)(jt + j) * FO_ + fq]);
        }
        e2reg[0] = *reinterpret_cast<const float4*>(&e2b[jt + jl0]);
        e2reg[1] = *reinterpret_cast<const float4*>(&e2b[jt + jl0 + 4]);
        c2reg = *reinterpret_cast<const float2*>(
            &hb[(size_t)(i0 + wi) * FO_ + (jt >> 4)]);
    };

    auto phaseW = [&](int buf) {         // stage tile data from regs into bufs[buf]
        #pragma unroll
        for (int it = 0; it < 2; ++it) {
            const int idx = it * 256 + t;
            const int j = idx >> 4, fq = (idx & 15) * 4;
            *reinterpret_cast<float4*>(&h_lds[buf][j][fq]) = hreg[it];
        }
        const float cg = S1 * ((ws < 2) ? c2reg.x : c2reg.y);  // g = i//16 select
        const int   aa[8] = { areg[0].x, areg[0].y, areg[0].z, areg[0].w,
                              areg[1].x, areg[1].y, areg[1].z, areg[1].w };
        const float ee[8] = { e2reg[0].x, e2reg[0].y, e2reg[0].z, e2reg[0].w,
                              e2reg[1].x, e2reg[1].y, e2reg[1].z, e2reg[1].w };
        #pragma unroll
        for (int dd = 0; dd < 8; ++dd) {
            const float ev = fmaxf(cg + ee[dd], 0.f);
            const float w  = aa[dd] ? __expf(ev) : 0.f;
            denreg += w;
            wT[buf][jl0 + dd][wi] = w;
        }
    };

    auto phaseG = [&](int buf) {
        #pragma unroll 8
        for (int jl = 0; jl < 32; ++jl) {
            const float4 wv = *reinterpret_cast<const float4*>(&wT[buf][jl][tyg * 4]);
            const float4 hv = *reinterpret_cast<const float4*>(&h_lds[buf][jl][tx * 4]);
            acc[0][0] = fmaf(wv.x, hv.x, acc[0][0]); acc[0][1] = fmaf(wv.x, hv.y, acc[0][1]);
            acc[0][2] = fmaf(wv.x, hv.z, acc[0][2]); acc[0][3] = fmaf(wv.x, hv.w, acc[0][3]);
            acc[1][0] = fmaf(wv.y, hv.x, acc[1][0]); acc[1][1] = fmaf(wv.y, hv.y, acc[1][1]);
            acc[1][2] = fmaf(wv.y, hv.z, acc[1][2]); acc[1][3] = fmaf(wv.y, hv.w, acc[1][3]);
            acc[2][0] = fmaf(wv.z, hv.x, acc[2][0]); acc[2][1] = fmaf(wv.z, hv.y, acc[2][1]);
            acc[2][2] = fmaf(wv.z, hv.z, acc[2][2]); acc[2][3] = fmaf(wv.z, hv.w, acc[2][3]);
            acc[3][0] = fmaf(wv.w, hv.x, acc[3][0]); acc[3][1] = fmaf(wv.w, hv.y, acc[3][1]);
            acc[3][2] = fmaf(wv.w, hv.z, acc[3][2]); acc[3][3] = fmaf(wv.w, hv.w, acc[3][3]);
        }
    };

    // prologue: tile 0 staged directly, tile 1 prefetched
    prefetch(0);
    phaseW(0);
    prefetch(1);
    __syncthreads();

    int cur = 0;
    #pragma unroll 1
    for (int tile = 0; tile < 32; ++tile) {
        if (tile < 31) phaseW(cur ^ 1);      // stage tile+1 (regs -> nxt buffers)
        if (tile < 30) prefetch(tile + 2);   // issue loads for tile+2
        phaseG(cur);                         // GEMM on current tile
        __syncthreads();                     // single barrier per tile
        cur ^= 1;
    }

    den_lds[wi][ws] = denreg;
    __syncthreads();

    #pragma unroll
    for (int mi = 0; mi < 4; ++mi) {
        const int i = tyg * 4 + mi;
        const float4 dv = *reinterpret_cast<const float4*>(&den_lds[i][0]);
        const float inv = 1.0f / (dv.x + dv.y + dv.z + dv.w);
        float v[4];
        #pragma unroll
        for (int q = 0; q < 4; ++q) {
            const float x = acc[mi][q] * inv;
            v[q] = (x > 0.f) ? x : expm1f(x);
        }
        float4 o; o.x = v[0]; o.y = v[1]; o.z = v[2]; o.w = v[3];
        *reinterpret_cast<float4*>(
            &out[((size_t)b * N_ + i0 + i) * FO_ + tx * 4]) = o;
    }
}

extern "C" void kernel_launch(void* const* d_in, const int* in_sizes, int n_in,
                              void* d_out, int out_size, void* d_ws, size_t ws_size,
                              hipStream_t stream) {
    const float* input = (const float*)d_in[0];   // [64][1024][256] f32
    const int*   adj   = (const int*)d_in[1];     // [64][1024][1024] i32
    const float* W     = (const float*)d_in[2];   // [256][64] f32
    const float* a     = (const float*)d_in[3];   // [128] f32
    float* out = (float*)d_out;                   // [64][1024][64] f32

    float* h  = (float*)d_ws;                                             // 16 MiB
    float* e2 = (float*)((char*)d_ws + (size_t)B_ * N_ * FO_ * sizeof(float));

    k1_hproj<<<dim3((B_ * N_) / 64), dim3(256), 0, stream>>>(input, W, a, h, e2);
    k2_attn<<<dim3(N_ / 64, B_), dim3(256), 0, stream>>>(h, adj, a, e2, out);
}

// Round 3
// 442.172 us; speedup vs baseline: 1.2013x; 1.2013x over previous
//
#include <hip/hip_runtime.h>
#include <math.h>

#define B_   64
#define N_   1024
#define FIN_ 256
#define FO_  64

typedef __attribute__((ext_vector_type(4))) float f32x4;
typedef __attribute__((ext_vector_type(8))) short short8;

__device__ __forceinline__ unsigned short f2bf_rne(float f) {
    union { float f; unsigned u; } v; v.f = f;
    const unsigned r = v.u + 0x7fffu + ((v.u >> 16) & 1u);
    return (unsigned short)(r >> 16);
}
__device__ __forceinline__ float bf2f(unsigned short h) {
    union { unsigned u; float f; } v; v.u = ((unsigned)h) << 16;
    return v.f;
}

// ---------------------------------------------------------------------------
// k0: transpose + hi/lo-split W[256][64] -> WThi/WTlo[64 f][256 k] bf16.
// Tiny (16384 elems); runs every call (ws is re-poisoned by the harness).
// ---------------------------------------------------------------------------
__global__ void k0_wt(const float* __restrict__ W,
                      unsigned short* __restrict__ WThi,
                      unsigned short* __restrict__ WTlo)
{
    const int idx = blockIdx.x * 256 + threadIdx.x;   // 0..16383
    const int k = idx >> 6, f = idx & 63;
    const float w = W[idx];
    const unsigned short hi = f2bf_rne(w);
    const unsigned short lo = f2bf_rne(w - bf2f(hi));
    WThi[f * FIN_ + k] = hi;
    WTlo[f * FIN_ + k] = lo;
}

// ---------------------------------------------------------------------------
// k1: h = input @ W via split-bf16 MFMA (3 terms: hi*hi + hi*lo + lo*hi ->
// f32-equivalent h). Block = 64 rows x 64 f, 4 waves, K chunked by 64.
// Outputs: hbT/hrT[b][f][j] bf16 (split h, TRANSPOSED for k2's B-frags),
//          e2[b*N+j] f32 (= h . a2).
// A/B LDS tiles are [row][64k] bf16 with chunk-XOR swizzle (c ^= row&7) so
// MFMA frag reads are bank-saturated (64 distinct 16B chunks / wave).
// ---------------------------------------------------------------------------
__global__ __launch_bounds__(256, 4) void k1_hproj(
    const float* __restrict__ input,
    const unsigned short* __restrict__ WThi,
    const unsigned short* __restrict__ WTlo,
    const float* __restrict__ a,
    unsigned short* __restrict__ hbT,
    unsigned short* __restrict__ hrT,
    float* __restrict__ e2)
{
    __shared__ union {
        struct { unsigned short Ahi[64*64], Alo[64*64], Bhi[64*64], Blo[64*64]; } s;
        struct { unsigned short hb[64*72], hr[64*72]; } e;   // [f][72] padded rows
    } u;

    const int t  = threadIdx.x;
    const int r0 = blockIdx.x * 64;
    const int b  = blockIdx.x >> 4;
    const int jb = r0 & (N_ - 1);

    const int l = t & 63, lm = l & 15, lk = l >> 4, wm0 = (t >> 6) * 16;

    f32x4 acc[4] = {};
    float4 iv[2][2];
    short8 wh[2], wl[2];

    auto load_chunk = [&](int c0) {
        #pragma unroll
        for (int q = 0; q < 2; ++q) {
            const int ci = t * 2 + q;            // 0..511 chunk id
            const int row = ci >> 3, cc = ci & 7;
            iv[q][0] = *reinterpret_cast<const float4*>(
                &input[(size_t)(r0 + row) * FIN_ + c0 + cc * 8]);
            iv[q][1] = *reinterpret_cast<const float4*>(
                &input[(size_t)(r0 + row) * FIN_ + c0 + cc * 8 + 4]);
            wh[q] = *reinterpret_cast<const short8*>(&WThi[row * FIN_ + c0 + cc * 8]);
            wl[q] = *reinterpret_cast<const short8*>(&WTlo[row * FIN_ + c0 + cc * 8]);
        }
    };
    auto store_chunk = [&]() {
        #pragma unroll
        for (int q = 0; q < 2; ++q) {
            const int ci = t * 2 + q;
            const int row = ci >> 3, cc = ci & 7;
            const int pos = (cc ^ (row & 7)) * 8;
            alignas(16) float xv[8];
            *reinterpret_cast<float4*>(&xv[0]) = iv[q][0];
            *reinterpret_cast<float4*>(&xv[4]) = iv[q][1];
            alignas(16) unsigned short h8[8], l8[8];
            #pragma unroll
            for (int e = 0; e < 8; ++e) {
                h8[e] = f2bf_rne(xv[e]);
                l8[e] = f2bf_rne(xv[e] - bf2f(h8[e]));
            }
            *reinterpret_cast<short8*>(&u.s.Ahi[row * 64 + pos]) = *reinterpret_cast<short8*>(h8);
            *reinterpret_cast<short8*>(&u.s.Alo[row * 64 + pos]) = *reinterpret_cast<short8*>(l8);
            *reinterpret_cast<short8*>(&u.s.Bhi[row * 64 + pos]) = wh[q];
            *reinterpret_cast<short8*>(&u.s.Blo[row * 64 + pos]) = wl[q];
        }
    };
    auto compute = [&]() {
        #pragma unroll
        for (int ks = 0; ks < 2; ++ks) {
            const int mrow = wm0 + lm;
            const int ac = (((ks << 2) + lk) ^ (mrow & 7)) * 8;
            const short8 ah = *reinterpret_cast<const short8*>(&u.s.Ahi[mrow * 64 + ac]);
            const short8 al = *reinterpret_cast<const short8*>(&u.s.Alo[mrow * 64 + ac]);
            #pragma unroll
            for (int nt = 0; nt < 4; ++nt) {
                const int fr = nt * 16 + lm;
                const int bc = (((ks << 2) + lk) ^ (fr & 7)) * 8;
                const short8 bh = *reinterpret_cast<const short8*>(&u.s.Bhi[fr * 64 + bc]);
                const short8 bl = *reinterpret_cast<const short8*>(&u.s.Blo[fr * 64 + bc]);
                acc[nt] = __builtin_amdgcn_mfma_f32_16x16x32_bf16(ah, bh, acc[nt], 0, 0, 0);
                acc[nt] = __builtin_amdgcn_mfma_f32_16x16x32_bf16(ah, bl, acc[nt], 0, 0, 0);
                acc[nt] = __builtin_amdgcn_mfma_f32_16x16x32_bf16(al, bh, acc[nt], 0, 0, 0);
            }
        }
    };

    load_chunk(0);
    #pragma unroll 1
    for (int c = 0; c < 4; ++c) {
        store_chunk();
        __syncthreads();
        if (c < 3) load_chunk((c + 1) * 64);
        compute();
        __syncthreads();
    }

    // epilogue: e2 + split h into u.e ([f][72] bf16, 2-way-max bank writes)
    float ap[4];
    #pragma unroll
    for (int nt = 0; nt < 4; ++nt) ap[nt] = a[FO_ + nt * 16 + lm];

    #pragma unroll
    for (int reg = 0; reg < 4; ++reg) {
        const int row = wm0 + lk * 4 + reg;      // C layout: row=(l>>4)*4+reg
        float e2p = 0.f;
        #pragma unroll
        for (int nt = 0; nt < 4; ++nt) {
            const float hv = acc[nt][reg];
            e2p += hv * ap[nt];
            const unsigned short hh = f2bf_rne(hv);
            const unsigned short hr = f2bf_rne(hv - bf2f(hh));
            const int f = nt * 16 + lm;          // C layout: col=l&15
            u.e.hb[f * 72 + row] = hh;
            u.e.hr[f * 72 + row] = hr;
        }
        e2p += __shfl_xor(e2p, 1);
        e2p += __shfl_xor(e2p, 2);
        e2p += __shfl_xor(e2p, 4);
        e2p += __shfl_xor(e2p, 8);
        if (lm == 0) e2[r0 + row] = e2p;
    }
    __syncthreads();

    // coalesced transposed store: hbT/hrT[(b*64+f)*1024 + jb + 0..63]
    {
        const int f = t >> 2, seg = t & 3;
        const size_t gb = ((size_t)(b * FO_ + f)) * N_ + jb + seg * 16;
        *reinterpret_cast<short8*>(&hbT[gb]) =
            *reinterpret_cast<const short8*>(&u.e.hb[f * 72 + seg * 16]);
        *reinterpret_cast<short8*>(&hbT[gb + 8]) =
            *reinterpret_cast<const short8*>(&u.e.hb[f * 72 + seg * 16 + 8]);
        *reinterpret_cast<short8*>(&hrT[gb]) =
            *reinterpret_cast<const short8*>(&u.e.hr[f * 72 + seg * 16]);
        *reinterpret_cast<short8*>(&hrT[gb + 8]) =
            *reinterpret_cast<const short8*>(&u.e.hr[f * 72 + seg * 16 + 8]);
    }
}

// ---------------------------------------------------------------------------
// k2: fused masked softmax attention + PV + ELU, PV via split-bf16 MFMA.
//   e1 collapses (idx==j//16 for all f): e[b,i,j]=relu(S1*h[b,i,j>>4]+e2[b,j])
//   w = adj ? exp(e) : 0 (single pass, no max: unmasked e>=0 bounded ~45;
//   masked weight exactly 0, matching reference exp(-9e15-m) underflow).
//   Numerator: sum_j (whi+wlo)_j * (hb+hr)_j via 3-term MFMA (f32-equiv);
//   denominator: f32 sum of the SAME (whi+wlo) -> ratios preserved.
// Block = 64 i-rows, 4 waves (16 rows each), j-tiles of 32, double-buffered
// LDS, register prefetch 2 tiles ahead, 1 barrier/tile.
// ---------------------------------------------------------------------------
__global__ __launch_bounds__(256, 4) void k2_attn(
    const unsigned short* __restrict__ hbT,
    const unsigned short* __restrict__ hrT,
    const int*   __restrict__ adj,
    const float* __restrict__ a,
    const float* __restrict__ e2,
    float* __restrict__ out)
{
    __shared__ unsigned short whi_lds[2][64*32], wlo_lds[2][64*32];
    __shared__ unsigned short hb_lds [2][64*32], hr_lds [2][64*32];
    __shared__ float den_lds[64][4];

    const int t  = threadIdx.x;
    const int b  = blockIdx.y;
    const int i0 = blockIdx.x * 64;

    const int wi = t >> 2, ws = t & 3, jl0 = ws * 8;     // weight/staging roles
    const int l = t & 63, lm = l & 15, lk = l >> 4, wm0 = (t >> 6) * 16;

    const int*   adjrow = adj + ((size_t)b * N_ + i0 + wi) * N_;
    const float* e2b    = e2 + (size_t)b * N_;
    const unsigned short* hbTb = hbT + (size_t)b * FO_ * N_;
    const unsigned short* hrTb = hrT + (size_t)b * FO_ * N_;

    float S1 = 0.f;
    #pragma unroll
    for (int f = 0; f < FO_; f += 4) {
        const float4 av = *reinterpret_cast<const float4*>(&a[f]);
        S1 += av.x + av.y + av.z + av.w;
    }

    f32x4 acc[4] = {};
    float denreg = 0.f;

    int4   areg[2];
    short8 hbreg, hrreg;
    float4 e2r[2];
    float  c2r;

    auto prefetch = [&](int tile) {
        const int jt = tile * 32;
        areg[0] = *reinterpret_cast<const int4*>(&adjrow[jt + jl0]);
        areg[1] = *reinterpret_cast<const int4*>(&adjrow[jt + jl0 + 4]);
        hbreg = *reinterpret_cast<const short8*>(&hbTb[(size_t)wi * N_ + jt + ws * 8]);
        hrreg = *reinterpret_cast<const short8*>(&hrTb[(size_t)wi * N_ + jt + ws * 8]);
        e2r[0] = *reinterpret_cast<const float4*>(&e2b[jt + jl0]);
        e2r[1] = *reinterpret_cast<const float4*>(&e2b[jt + jl0 + 4]);
        const int g = (jt >> 4) + (ws >> 1);             // f-index j>>4 for this slice
        c2r = bf2f(hbTb[(size_t)g * N_ + i0 + wi]) + bf2f(hrTb[(size_t)g * N_ + i0 + wi]);
    };

    auto phaseW = [&](int buf) {
        *reinterpret_cast<short8*>(&hb_lds[buf][wi * 32 + ws * 8]) = hbreg;
        *reinterpret_cast<short8*>(&hr_lds[buf][wi * 32 + ws * 8]) = hrreg;
        const float cg = S1 * c2r;
        const int aa[8] = { areg[0].x, areg[0].y, areg[0].z, areg[0].w,
                            areg[1].x, areg[1].y, areg[1].z, areg[1].w };
        alignas(16) float ee[8];
        *reinterpret_cast<float4*>(&ee[0]) = e2r[0];
        *reinterpret_cast<float4*>(&ee[4]) = e2r[1];
        alignas(16) unsigned short w_hi[8], w_lo[8];
        #pragma unroll
        for (int d = 0; d < 8; ++d) {
            const float ev = fmaxf(cg + ee[d], 0.f);
            const float w  = aa[d] ? __expf(ev) : 0.f;
            const unsigned short hi = f2bf_rne(w);
            const unsigned short lo = f2bf_rne(w - bf2f(hi));
            w_hi[d] = hi; w_lo[d] = lo;
            denreg += bf2f(hi) + bf2f(lo);               // exactly matches numerator
        }
        *reinterpret_cast<short8*>(&whi_lds[buf][wi * 32 + jl0]) = *reinterpret_cast<short8*>(w_hi);
        *reinterpret_cast<short8*>(&wlo_lds[buf][wi * 32 + jl0]) = *reinterpret_cast<short8*>(w_lo);
    };

    auto phaseG = [&](int buf) {
        const short8 awh = *reinterpret_cast<const short8*>(&whi_lds[buf][(wm0 + lm) * 32 + lk * 8]);
        const short8 awl = *reinterpret_cast<const short8*>(&wlo_lds[buf][(wm0 + lm) * 32 + lk * 8]);
        #pragma unroll
        for (int nt = 0; nt < 4; ++nt) {
            const int fr = nt * 16 + lm;
            const short8 bh = *reinterpret_cast<const short8*>(&hb_lds[buf][fr * 32 + lk * 8]);
            const short8 br = *reinterpret_cast<const short8*>(&hr_lds[buf][fr * 32 + lk * 8]);
            acc[nt] = __builtin_amdgcn_mfma_f32_16x16x32_bf16(awh, bh, acc[nt], 0, 0, 0);
            acc[nt] = __builtin_amdgcn_mfma_f32_16x16x32_bf16(awh, br, acc[nt], 0, 0, 0);
            acc[nt] = __builtin_amdgcn_mfma_f32_16x16x32_bf16(awl, bh, acc[nt], 0, 0, 0);
        }
    };

    prefetch(0);
    phaseW(0);
    prefetch(1);
    __syncthreads();

    int cur = 0;
    #pragma unroll 1
    for (int tile = 0; tile < 32; ++tile) {
        if (tile < 31) phaseW(cur ^ 1);
        if (tile < 30) prefetch(tile + 2);
        phaseG(cur);
        __syncthreads();
        cur ^= 1;
    }

    den_lds[wi][ws] = denreg;
    __syncthreads();

    #pragma unroll
    for (int reg = 0; reg < 4; ++reg) {
        const int i = wm0 + lk * 4 + reg;                // C layout row
        const float4 dv = *reinterpret_cast<const float4*>(&den_lds[i][0]);
        const float inv = 1.0f / (dv.x + dv.y + dv.z + dv.w);
        #pragma unroll
        for (int nt = 0; nt < 4; ++nt) {
            const float x = acc[nt][reg] * inv;
            const float y = (x > 0.f) ? x : expm1f(x);
            out[((size_t)b * N_ + i0 + i) * FO_ + nt * 16 + lm] = y;
        }
    }
}

extern "C" void kernel_launch(void* const* d_in, const int* in_sizes, int n_in,
                              void* d_out, int out_size, void* d_ws, size_t ws_size,
                              hipStream_t stream) {
    const float* input = (const float*)d_in[0];   // [64][1024][256] f32
    const int*   adj   = (const int*)d_in[1];     // [64][1024][1024] i32
    const float* W     = (const float*)d_in[2];   // [256][64] f32
    const float* a     = (const float*)d_in[3];   // [128] f32
    float* out = (float*)d_out;                   // [64][1024][64] f32

    char* ws = (char*)d_ws;
    unsigned short* hbT  = (unsigned short*)(ws);                       // 8 MiB
    unsigned short* hrT  = (unsigned short*)(ws + (8u << 20));          // 8 MiB
    float*          e2   = (float*)(ws + (16u << 20));                  // 256 KiB
    unsigned short* WThi = (unsigned short*)(ws + (16u << 20) + (256u << 10));
    unsigned short* WTlo = WThi + FO_ * FIN_;

    k0_wt  <<<dim3(64),                 dim3(256), 0, stream>>>(W, WThi, WTlo);
    k1_hproj<<<dim3((B_ * N_) / 64),    dim3(256), 0, stream>>>(input, WThi, WTlo, a, hbT, hrT, e2);
    k2_attn<<<dim3(N_ / 64, B_),        dim3(256), 0, stream>>>(hbT, hrT, adj, a, e2, out);
}